// Round 3
// baseline (910.981 us; speedup 1.0000x reference)
//
#include <hip/hip_runtime.h>

typedef __attribute__((ext_vector_type(8))) __bf16 bf16x8;
typedef __attribute__((ext_vector_type(4))) __bf16 bf16x4;
typedef __attribute__((ext_vector_type(4))) float f32x4;

#define TOKENS 16384   // B*T
#define DDIM   2048
#define LAT    256
#define FFND   1024

// ---------------------------------------------------------------------------
// Batched transpose + fp32->bf16 convert: src (batch, R, C) f32 -> dst (batch, C, R) bf16
// ---------------------------------------------------------------------------
__global__ void transpose_f32_bf16(const float* __restrict__ src, __bf16* __restrict__ dst,
                                   int R, int C) {
  __shared__ float tile[32][33];  // +1 pad breaks bank conflicts
  const int b = blockIdx.z;
  src += (size_t)b * R * C;
  dst += (size_t)b * R * C;
  const int c0 = blockIdx.x * 32, r0 = blockIdx.y * 32;
  const int tx = threadIdx.x & 31, ty = threadIdx.x >> 5;  // 256 threads: ty 0..7
  for (int i = ty; i < 32; i += 8)
    tile[i][tx] = src[(size_t)(r0 + i) * C + c0 + tx];
  __syncthreads();
  for (int i = ty; i < 32; i += 8)
    dst[(size_t)(c0 + i) * R + r0 + tx] = (__bf16)tile[tx][i];
}

// ---------------------------------------------------------------------------
// K0a: partial eo = silu(emb) @ emb_W over a 256-wide k-chunk.
// grid (16 j-tiles, 8 k-chunks), block 256. pp[(kc*4+b)*4096 + j]
// ---------------------------------------------------------------------------
__global__ void k0_partial(const float* __restrict__ emb, const float* __restrict__ embW,
                           float* __restrict__ pp) {
  __shared__ float se[4 * 256];
  const int tid = threadIdx.x;
  const int kc = blockIdx.y;
  const int kb = kc * 256;
  for (int i = tid; i < 1024; i += 256) {
    const int bb = i >> 8, kk = i & 255;
    float v = emb[bb * 2048 + kb + kk];
    se[i] = v / (1.f + __expf(-v));
  }
  __syncthreads();
  const int j = blockIdx.x * 256 + tid;
  float a0 = 0.f, a1 = 0.f, a2 = 0.f, a3 = 0.f;
  for (int k = 0; k < 256; ++k) {
    float wv = embW[(size_t)(kb + k) * 4096 + j];
    a0 += se[k] * wv;
    a1 += se[256 + k] * wv;
    a2 += se[512 + k] * wv;
    a3 += se[768 + k] * wv;
  }
  pp[(size_t)(kc * 4 + 0) * 4096 + j] = a0;
  pp[(size_t)(kc * 4 + 1) * 4096 + j] = a1;
  pp[(size_t)(kc * 4 + 2) * 4096 + j] = a2;
  pp[(size_t)(kc * 4 + 3) * 4096 + j] = a3;
}

// K0b: reduce partials + bias -> ss[b*4096 + j] (fp32)
__global__ void k0_reduce(const float* __restrict__ pp, const float* __restrict__ embb,
                          float* __restrict__ ss) {
  const int j = blockIdx.x * 256 + threadIdx.x;
  const float bb = embb[j];
#pragma unroll
  for (int b = 0; b < 4; ++b) {
    float s = bb;
#pragma unroll
    for (int kc = 0; kc < 8; ++kc) s += pp[(size_t)(kc * 4 + b) * 4096 + j];
    ss[b * 4096 + j] = s;
  }
}

// ---------------------------------------------------------------------------
// K1: fused expert FFN. Block = 64 tokens x 1 expert, 4 waves.
// y[m, e*256+l] = (GELU(x_e @ W1[e] + b1[e]) @ W2[e]) + b2[e]   (y stored bf16)
// x is fp32 -> converted to bf16 in LDS. Weights pre-transposed bf16.
// ---------------------------------------------------------------------------
__launch_bounds__(256, 2)
__global__ void k1_expert_ffn(const float* __restrict__ x, const __bf16* __restrict__ W1T,
                              const float* __restrict__ b1, const __bf16* __restrict__ W2T,
                              const float* __restrict__ b2, __bf16* __restrict__ y) {
  __shared__ __bf16 xs[64 * 256];     // 32 KB  x tile [m][l] (bf16)
  __shared__ __bf16 hs[64 * 256];     // 32 KB  gelu(h) chunk [m][f_local]

  const int tid = threadIdx.x;
  const int w = tid >> 6;
  const int lane = tid & 63;
  const int q = lane >> 4;
  const int ln = lane & 15;
  const int m0 = blockIdx.x * 64;
  const int e = blockIdx.y;

  // stage x tile (64 x 256 fp32) -> bf16 LDS; 64 lanes x float4 per row-pass
  {
    const int r0 = tid >> 6;          // 4 rows per pass
    const int c = (tid & 63) * 4;     // 4 floats
#pragma unroll
    for (int p = 0; p < 16; ++p) {
      const int r = r0 + p * 4;
      f32x4 v = *(const f32x4*)(x + (size_t)(m0 + r) * DDIM + e * LAT + c);
      bf16x4 o;
      o[0] = (__bf16)v[0]; o[1] = (__bf16)v[1]; o[2] = (__bf16)v[2]; o[3] = (__bf16)v[3];
      *(bf16x4*)(xs + r * 256 + c) = o;
    }
  }

  f32x4 acc_y[4][4];
#pragma unroll
  for (int j = 0; j < 4; ++j) {
    float bv = b2[e * LAT + w * 64 + j * 16 + ln];
    f32x4 t = {bv, bv, bv, bv};
#pragma unroll
    for (int i = 0; i < 4; ++i) acc_y[i][j] = t;
  }

  __syncthreads();  // xs ready

  for (int fc = 0; fc < 4; ++fc) {  // FFN dim in 4 chunks of 256
    f32x4 acc_h[4][4];
#pragma unroll
    for (int j = 0; j < 4; ++j) {
      float bv = b1[e * FFND + fc * 256 + w * 64 + j * 16 + ln];
      f32x4 t = {bv, bv, bv, bv};
#pragma unroll
      for (int i = 0; i < 4; ++i) acc_h[i][j] = t;
    }

    // ---- GEMM1: h_chunk(64x256) = xs @ W1T-rows (B-frags direct from global)
    const __bf16* w1src = W1T + ((size_t)e * FFND + fc * 256 + w * 64) * LAT;
    for (int k0 = 0; k0 < 256; k0 += 32) {
      bf16x8 af[4], bfr[4];
#pragma unroll
      for (int j = 0; j < 4; ++j)
        bfr[j] = *(const bf16x8*)(w1src + (size_t)(j * 16 + ln) * LAT + k0 + q * 8);
#pragma unroll
      for (int i = 0; i < 4; ++i)
        af[i] = *(const bf16x8*)(xs + (i * 16 + ln) * 256 + k0 + q * 8);
#pragma unroll
      for (int i = 0; i < 4; ++i)
#pragma unroll
        for (int j = 0; j < 4; ++j)
          acc_h[i][j] = __builtin_amdgcn_mfma_f32_16x16x32_bf16(af[i], bfr[j], acc_h[i][j], 0, 0, 0);
    }

    __syncthreads();  // previous chunk's hs fully consumed by all waves

    // exact GELU, pack to LDS (C-layout -> A-layout transform)
#pragma unroll
    for (int i = 0; i < 4; ++i)
#pragma unroll
      for (int j = 0; j < 4; ++j) {
        const int fl = w * 64 + j * 16 + ln;
#pragma unroll
        for (int r = 0; r < 4; ++r) {
          float vv = acc_h[i][j][r];
          float ge = 0.5f * vv * (1.0f + erff(vv * 0.70710678118654752f));
          hs[(i * 16 + q * 4 + r) * 256 + fl] = (__bf16)ge;
        }
      }

    __syncthreads();  // hs ready

    // ---- GEMM2: acc_y += hs(64x256) @ W2T-rows (B-frags direct from global)
    const __bf16* w2src = W2T + ((size_t)e * LAT + w * 64) * FFND + fc * 256;
    for (int k0 = 0; k0 < 256; k0 += 32) {
      bf16x8 af[4], bfr[4];
#pragma unroll
      for (int j = 0; j < 4; ++j)
        bfr[j] = *(const bf16x8*)(w2src + (size_t)(j * 16 + ln) * FFND + k0 + q * 8);
#pragma unroll
      for (int i = 0; i < 4; ++i)
        af[i] = *(const bf16x8*)(hs + (i * 16 + ln) * 256 + k0 + q * 8);
#pragma unroll
      for (int i = 0; i < 4; ++i)
#pragma unroll
        for (int j = 0; j < 4; ++j)
          acc_y[i][j] = __builtin_amdgcn_mfma_f32_16x16x32_bf16(af[i], bfr[j], acc_y[i][j], 0, 0, 0);
    }
  }

  // store y (bf16)
#pragma unroll
  for (int i = 0; i < 4; ++i)
#pragma unroll
    for (int j = 0; j < 4; ++j) {
      const int l = w * 64 + j * 16 + ln;
#pragma unroll
      for (int r = 0; r < 4; ++r) {
        const int m = i * 16 + q * 4 + r;
        y[(size_t)(m0 + m) * DDIM + e * LAT + l] = (__bf16)acc_y[i][j][r];
      }
    }
}

// ---------------------------------------------------------------------------
// K2: per-token LN + (1+scale)/shift modulation + SiLU, in place on y (bf16).
// ---------------------------------------------------------------------------
__global__ void k2_ln_mod_silu(const float* __restrict__ ss, const float* __restrict__ g,
                               const float* __restrict__ bb, __bf16* __restrict__ y) {
  __shared__ float red[8];
  const int t = blockIdx.x;     // token
  const int b = t >> 12;        // batch = token / 4096
  const int tid = threadIdx.x;
  __bf16* row = y + (size_t)t * DDIM;
  bf16x8 v8 = *(bf16x8*)(row + tid * 8);
  float v[8], s = 0.f, sq = 0.f;
#pragma unroll
  for (int i = 0; i < 8; ++i) {
    v[i] = (float)v8[i];
    s += v[i];
    sq += v[i] * v[i];
  }
#pragma unroll
  for (int off = 32; off > 0; off >>= 1) {
    s += __shfl_down(s, off);
    sq += __shfl_down(sq, off);
  }
  if ((tid & 63) == 0) {
    red[tid >> 6] = s;
    red[4 + (tid >> 6)] = sq;
  }
  __syncthreads();
  const float S = red[0] + red[1] + red[2] + red[3];
  const float SQ = red[4] + red[5] + red[6] + red[7];
  const float mean = S * (1.f / DDIM);
  const float var = SQ * (1.f / DDIM) - mean * mean;
  const float rstd = rsqrtf(var + 1e-5f);
  const float* sc = ss + (size_t)b * 2 * DDIM;
#pragma unroll
  for (int i = 0; i < 8; ++i) {
    const int d = tid * 8 + i;
    float hn = (v[i] - mean) * rstd * g[d] + bb[d];
    hn = hn * (1.f + sc[d]) + sc[DDIM + d];
    float si = hn / (1.f + __expf(-hn));
    v8[i] = (__bf16)si;
  }
  *(bf16x8*)(row + tid * 8) = v8;
}

// ---------------------------------------------------------------------------
// K3: out[m_base..] = x + a @ out_W + out_b (fp32 out). 128x128 tile, 4 waves.
// a (y) bf16, oWT bf16, x/ob/out fp32.
// ---------------------------------------------------------------------------
__launch_bounds__(256, 2)
__global__ void k3_proj(const __bf16* __restrict__ a, const __bf16* __restrict__ oWT,
                        const float* __restrict__ ob, const float* __restrict__ x,
                        float* __restrict__ out, int m_base) {
  __shared__ __bf16 As[128 * 64];  // 16 KB
  __shared__ __bf16 Bs[128 * 64];  // 16 KB
  const int tid = threadIdx.x;
  const int w = tid >> 6, lane = tid & 63, q = lane >> 4, ln = lane & 15;
  const int wm = w >> 1, wn = w & 1;
  const int m0 = m_base + blockIdx.x * 128, n0 = blockIdx.y * 128;
  f32x4 acc[4][4] = {};
  const int r0 = tid >> 3, c = (tid & 7) * 8;  // 8 threads/row, 32 rows/pass

  for (int k0 = 0; k0 < 2048; k0 += 64) {
    __syncthreads();  // protect As/Bs from previous iteration's readers
#pragma unroll
    for (int p = 0; p < 4; ++p) {
      const int r = r0 + p * 32;
      *(bf16x8*)(As + r * 64 + c) =
          *(const bf16x8*)(a + (size_t)(m0 + r) * DDIM + k0 + c);
      *(bf16x8*)(Bs + r * 64 + c) =
          *(const bf16x8*)(oWT + (size_t)(n0 + r) * DDIM + k0 + c);
    }
    __syncthreads();
#pragma unroll
    for (int ks = 0; ks < 64; ks += 32) {
      bf16x8 af[4], bfr[4];
#pragma unroll
      for (int i = 0; i < 4; ++i)
        af[i] = *(const bf16x8*)(As + (wm * 64 + i * 16 + ln) * 64 + ks + q * 8);
#pragma unroll
      for (int j = 0; j < 4; ++j)
        bfr[j] = *(const bf16x8*)(Bs + (wn * 64 + j * 16 + ln) * 64 + ks + q * 8);
#pragma unroll
      for (int i = 0; i < 4; ++i)
#pragma unroll
        for (int j = 0; j < 4; ++j)
          acc[i][j] = __builtin_amdgcn_mfma_f32_16x16x32_bf16(af[i], bfr[j], acc[i][j], 0, 0, 0);
    }
  }

  // epilogue: + out_b + residual x, store fp32
#pragma unroll
  for (int j = 0; j < 4; ++j) {
    const int n = n0 + wn * 64 + j * 16 + ln;
    const float bn = ob[n];
#pragma unroll
    for (int i = 0; i < 4; ++i)
#pragma unroll
      for (int r = 0; r < 4; ++r) {
        const int m = m0 + wm * 64 + i * 16 + q * 4 + r;
        float v = acc[i][j][r] + bn + x[(size_t)m * DDIM + n];
        out[(size_t)m * DDIM + n] = v;
      }
  }
}

// ---------------------------------------------------------------------------
// d_out is fp32 (16384 x 2048 = 134 MB) and doubles as phase-1 scratch:
//   W1T [0,4MB) bf16, W2T [4,8MB) bf16, pp [8MB,8.5MB) f32, ss [8.5MB,+64KB) f32
//   after k1: oWT1 over [0,8MB) bf16
// k3a (rows 2048..16383) reads oWT1, writes d_out [16MB,134MB).
// oWT2 then goes into ws[8,16MB) (y-rows 2048..4095 are dead after k3a);
// k3b (rows 0..2047) reads oWT2, writes d_out [0,16MB).
// d_ws usage: exactly 64 MB (y bf16).
// ---------------------------------------------------------------------------
extern "C" void kernel_launch(void* const* d_in, const int* in_sizes, int n_in,
                              void* d_out, int out_size, void* d_ws, size_t ws_size,
                              hipStream_t stream) {
  const float* x    = (const float*)d_in[0];
  const float* emb  = (const float*)d_in[1];
  const float* W1   = (const float*)d_in[2];
  const float* b1   = (const float*)d_in[3];
  const float* W2   = (const float*)d_in[4];
  const float* b2   = (const float*)d_in[5];
  const float* embW = (const float*)d_in[6];
  const float* embb = (const float*)d_in[7];
  const float* lng  = (const float*)d_in[8];
  const float* lnb  = (const float*)d_in[9];
  const float* outW = (const float*)d_in[10];
  const float* outb = (const float*)d_in[11];
  float* out = (float*)d_out;

  char* ob = (char*)d_out;
  __bf16* W1T  = (__bf16*)ob;                            // [0, 4MB)
  __bf16* W2T  = (__bf16*)(ob + (4 << 20));              // [4, 8MB)
  float*  pp   = (float*)(ob + (8 << 20));               // [8MB, +512KB)
  float*  ss   = (float*)(ob + (8 << 20) + (512 << 10)); // [8.5MB, +64KB)
  __bf16* oWT1 = (__bf16*)ob;                            // [0, 8MB) after k1
  __bf16* y    = (__bf16*)d_ws;                          // [0, 64MB)
  __bf16* oWT2 = (__bf16*)((char*)d_ws + (8 << 20));     // [8, 16MB), after k3a

  transpose_f32_bf16<<<dim3(32, 8, 8), 256, 0, stream>>>(W1, W1T, 256, 1024);
  transpose_f32_bf16<<<dim3(8, 32, 8), 256, 0, stream>>>(W2, W2T, 1024, 256);
  k0_partial<<<dim3(16, 8), 256, 0, stream>>>(emb, embW, pp);
  k0_reduce<<<16, 256, 0, stream>>>(pp, embb, ss);
  k1_expert_ffn<<<dim3(TOKENS / 64, 8), 256, 0, stream>>>(x, W1T, b1, W2T, b2, y);
  k2_ln_mod_silu<<<TOKENS, 256, 0, stream>>>(ss, lng, lnb, y);
  // W1T/W2T dead; overwrite with out_W^T (bf16)
  transpose_f32_bf16<<<dim3(64, 64, 1), 256, 0, stream>>>(outW, oWT1, 2048, 2048);
  // rows 2048..16383: reads oWT1 (d_out[0,8MB)), writes d_out[16MB,134MB)
  k3_proj<<<dim3(112, 16), 256, 0, stream>>>(y, oWT1, outb, x, out, 2048);
  // y-rows 2048..4095 (ws[8,16MB)) are dead now; stash a second out_W^T there
  transpose_f32_bf16<<<dim3(64, 64, 1), 256, 0, stream>>>(outW, oWT2, 2048, 2048);
  // rows 0..2047: reads oWT2 (ws), writes d_out[0,16MB)
  k3_proj<<<dim3(16, 16), 256, 0, stream>>>(y, oWT2, outb, x, out, 0);
}